// Round 14
// baseline (1476.317 us; speedup 1.0000x reference)
//
#include <hip/hip_runtime.h>

// CrossShareUnit: B=8192, L=1, DL=DM=1024, K=8
// out order: [l_out | m_out | l_attn | m_attn], each 8192*1024 fp32.

#define NB 8192
#define DD 1024

typedef __bf16 bf16x8 __attribute__((ext_vector_type(8)));
typedef float f32x4 __attribute__((ext_vector_type(4)));

__device__ __forceinline__ unsigned short f2bf(float f) {
  unsigned u = __float_as_uint(f);
  u += 0x7FFFu + ((u >> 16) & 1u);   // RNE to bf16
  return (unsigned short)(u >> 16);
}
__device__ __forceinline__ float bf2f(unsigned short h) {
  return __uint_as_float(((unsigned)h) << 16);
}

// B fragment-major layout (ushort index) for element (n, k):
//   chunk (n>>4, k>>5) of 1KB; within: lane (n&15)+16*((k>>3)&3) holds 16B.
// One wave B-fragment = one fully coalesced dwordx4 load.  [R12-verified]
__device__ __forceinline__ size_t bidx(int n, int k) {
  return ((size_t)(n >> 4) << 14) + ((k >> 5) << 9) + (((k >> 3) & 3) << 7) +
         ((n & 15) << 3) + (k & 7);
}

// ---- fused prep: [0,8192) split h -> Ahi/Alo; [8192,16384) transpose+split
// G -> fragment-major Bhi/Blo; [16384,17408) Wc^T cols + bc ----
__global__ __launch_bounds__(256) void prep_k(
    const float* __restrict__ h, const float* __restrict__ G,
    const float* __restrict__ w1, const float* __restrict__ b1,
    const float* __restrict__ w2, const float* __restrict__ b2, int J,
    unsigned short* __restrict__ Ahi, unsigned short* __restrict__ Alo,
    unsigned short* __restrict__ Bhi, unsigned short* __restrict__ Blo,
    float* __restrict__ bc) {
  __shared__ float t[32][33];
  __shared__ float w2row[256];
  const int bid = blockIdx.x;
  const int tid = threadIdx.x;
  if (bid < 8192) {
    int i = bid * 256 + tid;                    // n4 = 8192*1024/4
    float4 v = reinterpret_cast<const float4*>(h)[i];
    float vv[4] = {v.x, v.y, v.z, v.w};
    unsigned short hh[4], ll[4];
#pragma unroll
    for (int c = 0; c < 4; ++c) {
      hh[c] = f2bf(vv[c]);
      ll[c] = f2bf(vv[c] - bf2f(hh[c]));
    }
    reinterpret_cast<ushort4*>(Ahi)[i] = make_ushort4(hh[0], hh[1], hh[2], hh[3]);
    reinterpret_cast<ushort4*>(Alo)[i] = make_ushort4(ll[0], ll[1], ll[2], ll[3]);
  } else if (bid < 16384) {
    const int b = bid - 8192;
    const int c0 = (b & 255) * 32;
    const int d0 = (b >> 8) * 32;
    const int tx = tid & 31;
    const int tg = tid >> 5;
#pragma unroll
    for (int s = 0; s < 4; ++s) {
      int dr = tg * 4 + s;
      t[dr][tx] = G[(size_t)(d0 + dr) * 8192 + c0 + tx];
    }
    __syncthreads();
#pragma unroll
    for (int s = 0; s < 4; ++s) {
      int cr = tg * 4 + s;
      float v = t[tx][cr];                 // = G[d0+tx][c0+cr]
      size_t o = bidx(c0 + cr, d0 + tx);
      unsigned short hh = f2bf(v);
      Bhi[o] = hh;
      Blo[o] = f2bf(v - bf2f(hh));
    }
  } else {
    const int n = bid - 16384;
    if (tid < J) w2row[tid] = w2[n * J + tid];
    __syncthreads();
#pragma unroll
    for (int s = 0; s < 4; ++s) {
      int i = tid + s * 256;
      float acc = 0.f;
      for (int j = 0; j < J; ++j) acc = fmaf(w2row[j], w1[j * 1024 + i], acc);
      size_t o = bidx(8192 + n, i);
      unsigned short hh = f2bf(acc);
      Bhi[o] = hh;
      Blo[o] = f2bf(acc - bf2f(hh));
    }
    if (tid == 0) {
      float acc = 0.f;
      for (int j = 0; j < J; ++j) acc = fmaf(w2row[j], b1[j], acc);
      bc[n] = acc + b2[n];
    }
  }
}

// ============================================================================
// 256x256 GEMM: A via LDS (4x cross-wave reuse), B DIRECT global->reg from
// fragment-major Bt, prefetched ONE FULL TILE ahead into a second static
// register set (loop unrolled x2; no runtime set index -> no scratch).
// C[b,n]=sum_k Aseg[b,k]Bseg[n,k]; K=3072 as (Ahi,Bhi),(Alo,Bhi),(Ahi,Blo).
// Pipe balance: LDS/tile = 128KB A-reads + 32KB A-stage ~ 1900cy < MFMA
// 2480cy.  B from L2 spread over whole tile: ~34 B/cyc < 60 B/cyc L2/CU.
// Snake: mm0=(0,0){af,b0c} mm1=(0,1){af,b1c} mm2=(1,1){af2,b1c}
// mm3=(1,0){af2,b0c}.
//   p0: stage A0(t+1); mm0
//   p1: ldA af2<-A1(t); ldBdir b0n<-B0(t+1); mm1; WAITV4 [drain stgA0,
//       keep b0n]; SBAR (mid)
//   p2: ldA af<-A0(t+1); stage A1(t+1); mm2
//   p3: mm3; ldBdir b1n<-B1(t+1); WAITV4 [drain stgA1, keep b1n]; SBAR (end)
// In-order vmcnt ledger (outstanding): <=4 -> p0 +2 -> p1 +4 =10 -> W4
// -> 4 -> p2 +2 -> p3 +4 =10 -> W4 -> 4.  Every B set has a full tile
// (~2500cy) issue-to-use cover; A-stages drained one barrier before read.
// WAR (A LDS): each stage targets a region whose last consuming mm retired
// >=2 barriers earlier (R12-verified discipline).
// Tail: clamped data tile (redundant loads, dead buffer).  VGPR ~280 ok at
// launch_bounds(512,1) (the R6/R8 spills were the (512,2) 128-VGPR cap).
// Swizzle (rule #21, A only): LDS linear, global SOURCE slot ^= row&7,
// ds_read slot ^= row&7.  LDS = 64 KB.  1 block/CU, 8 waves.  R5 XCD map.
// ============================================================================
#define SBAR() do { asm volatile("" ::: "memory"); __builtin_amdgcn_s_barrier(); asm volatile("" ::: "memory"); } while (0)
#define WAITV4() asm volatile("s_waitcnt vmcnt(4)" ::: "memory")
#define WAITV8() asm volatile("s_waitcnt vmcnt(8)" ::: "memory")

#define GLOAD(SRC, DST)                                              \
  __builtin_amdgcn_global_load_lds(                                  \
      (const __attribute__((address_space(1))) void*)(SRC),          \
      (__attribute__((address_space(3))) void*)(lds + (DST)), 16, 0, 0)

__global__ __launch_bounds__(512, 1) void gemm_k(
    const unsigned short* __restrict__ Ahi_, const unsigned short* __restrict__ Alo_,
    const unsigned short* __restrict__ Bhi_, const unsigned short* __restrict__ Blo_,
    const float* __restrict__ hb, float* __restrict__ gvec, float* __restrict__ x) {
  __shared__ __align__(16) char lds[65536];
  const char* Ah = (const char*)Ahi_;
  const char* Al = (const char*)Alo_;
  const char* Bh = (const char*)Bhi_;
  const char* Bl = (const char*)Blo_;

  const int tid = threadIdx.x;
  const int lane = tid & 63;
  const int wid = tid >> 6;
  const int wm = wid >> 2, wn = wid & 3;   // wave: 64 A-rows x 32 B-cols per quadrant

  // XCD-aware (R5 map): each XCD owns a 4-row M-band; 4 neighbors share each
  // B panel; gvec blocks (bx>=32) dispatched last.
  const int bid = blockIdx.x;
  const int xcd = bid & 7;
  const int j = bid >> 3;                  // 0..143
  const int by = xcd * 4 + (j & 3);        // 0..31
  const int bx = j >> 2;                   // 0..35
  const int m0 = by * 256;
  const int n0 = bx * 256;
  const bool isg = (n0 >= 8192);
  const int nt = isg ? 16 : 48;            // gvec tiles: hi*hi only

  const int rowl = tid >> 3;                               // staged row 0..63
  const int colsw = ((tid & 7) ^ ((tid >> 3) & 7)) << 4;   // pre-swizzled src slot
  const int s0 = ((lane >> 4) ^ (lane & 7)) << 4;          // ds_read slot ks=0
  const int s1 = s0 ^ 64;                                  // ks=1

  f32x4 acc[4][4][2] = {};   // [q 0:(00) 1:(01) 2:(11) 3:(10)][f][g]

  // A staging only; q = A quarter (0: rows 0..127, 1: rows 128..255).
  auto stage = [&](int tl, int par, int q) {
    const char* mat = ((tl >> 4) == 1) ? Al : Ah;
    const char* src = mat + (size_t)(m0 + q * 128 + rowl) * 2048 + ((tl & 15) << 7) + colsw;
    const int dst = par * 32768 + q * 16384 + wid * 1024;
    GLOAD(src, dst);                      // rows 0..63 of quarter
    GLOAD(src + 64 * 2048, dst + 8192);   // rows 64..127
  };

  auto ldA = [&](bf16x8 (*d)[2], int qa, int cb) {
    const char* p = lds + cb + qa * 16384 + (wm * 64 + (lane & 15)) * 128;
#pragma unroll
    for (int f = 0; f < 4; ++f) {
      d[f][0] = *reinterpret_cast<const bf16x8*>(p + f * 2048 + s0);
      d[f][1] = *reinterpret_cast<const bf16x8*>(p + f * 2048 + s1);
    }
  };
  // B direct: fragment (n16, kb) = 1KB chunk at base + chunk*1024 + lane*16.
  auto ldBdir = [&](bf16x8 (*d)[2], int qn, int tl) {
    const char* base = ((tl >> 4) == 2) ? Bl : Bh;
#pragma unroll
    for (int g = 0; g < 2; ++g) {
      const size_t chunk =
          ((size_t)(n0 >> 4) + qn * 8 + wn * 2 + g) * 32 + ((tl & 15) << 1);
      const char* p = base + chunk * 1024 + lane * 16;
      d[g][0] = *reinterpret_cast<const bf16x8*>(p);
      d[g][1] = *reinterpret_cast<const bf16x8*>(p + 1024);
    }
  };
  auto mm = [&](f32x4 (*ac)[2], bf16x8 (*aa)[2], bf16x8 (*bb)[2]) {
#pragma unroll
    for (int f = 0; f < 4; ++f)
#pragma unroll
      for (int g = 0; g < 2; ++g) {
        ac[f][g] = __builtin_amdgcn_mfma_f32_16x16x32_bf16(aa[f][0], bb[g][0], ac[f][g], 0, 0, 0);
        ac[f][g] = __builtin_amdgcn_mfma_f32_16x16x32_bf16(aa[f][1], bb[g][1], ac[f][g], 0, 0, 0);
      }
  };

  bf16x8 af[4][2], af2[4][2];
  bf16x8 b0A[2][2], b1A[2][2], b0B[2][2], b1B[2][2];   // static ping-pong sets

  // prologue: stage A(0) into buf0 (4 glds); load B(0) into A-sets (8);
  // WAITV8 drains the stages, keeps the 8 B loads; barrier; read af<-A0(0).
  stage(0, 0, 0); stage(0, 0, 1);
  ldBdir(b0A, 0, 0);
  ldBdir(b1A, 1, 0);
  WAITV8();
  SBAR();
  ldA(af, 0, 0);

  auto body = [&](int t, bf16x8 (*b0c)[2], bf16x8 (*b1c)[2],
                  bf16x8 (*b0n)[2], bf16x8 (*b1n)[2]) {
    const int cb = (t & 1) * 32768;
    const int cbN = cb ^ 32768;
    const int parN = (t + 1) & 1;
    const int tn = (t + 1 < nt) ? (t + 1) : (nt - 1);   // clamped data, dead buffer
    // ---- p0: mm(0,0){af,b0c}; stage A0(t+1)
    stage(tn, parN, 0);
    __builtin_amdgcn_s_setprio(1);
    mm(acc[0], af, b0c);
    __builtin_amdgcn_s_setprio(0);
    // ---- p1: mm(0,1){af,b1c}; ldA af2<-A1(t); ldBdir b0n<-B0(t+1)
    ldA(af2, 1, cb);
    ldBdir(b0n, 0, tn);
    __builtin_amdgcn_s_setprio(1);
    mm(acc[1], af, b1c);
    __builtin_amdgcn_s_setprio(0);
    WAITV4();          // drain A0(t+1) stage; keep b0n in flight
    SBAR();            // mid-tile: A0(t+1) visible
    // ---- p2: mm(1,1){af2,b1c}; ldA af<-A0(t+1); stage A1(t+1)
    ldA(af, 0, cbN);
    stage(tn, parN, 1);
    __builtin_amdgcn_s_setprio(1);
    mm(acc[2], af2, b1c);
    __builtin_amdgcn_s_setprio(0);
    // ---- p3: mm(1,0){af2,b0c}; ldBdir b1n<-B1(t+1)
    ldBdir(b1n, 1, tn);
    __builtin_amdgcn_s_setprio(1);
    mm(acc[3], af2, b0c);
    __builtin_amdgcn_s_setprio(0);
    WAITV4();          // drain A1(t+1) stage; keep b1n in flight
    SBAR();            // tile-end: A1(t+1) visible
  };

  for (int tt = 0; tt < nt; tt += 2) {
    body(tt, b0A, b1A, b0B, b1B);
    body(tt + 1, b0B, b1B, b0A, b1A);
  }

  // ---- epilogue (registers only); acc: 0:(0,0) 1:(0,1) 2:(1,1) 3:(1,0) ----
  const int coll = lane & 15;
  const int rg = (lane >> 4) * 4;
  if (isg) {
#pragma unroll
    for (int q = 0; q < 4; ++q) {
      const int qm = (q >= 2);
      const int qn = (q == 1 || q == 2);
#pragma unroll
      for (int f = 0; f < 4; ++f)
#pragma unroll
        for (int rr = 0; rr < 4; ++rr) {
          const int row = m0 + qm * 128 + wm * 64 + f * 16 + rg + rr;
#pragma unroll
          for (int g = 0; g < 2; ++g) {
            const int gcol = (n0 - 8192) + qn * 128 + wn * 32 + g * 16 + coll;
            gvec[(size_t)row * 1024 + gcol] = acc[q][f][g][rr];
          }
        }
    }
  } else {
    const int kidx = n0 >> 10;
    const int ebase = (n0 & 1023) + wn * 32 + coll;
#pragma unroll
    for (int qm = 0; qm < 2; ++qm) {
      f32x4 (*acA)[2] = acc[qm ? 3 : 0];  // qn=0
      f32x4 (*acB)[2] = acc[qm ? 2 : 1];  // qn=1
#pragma unroll
      for (int f = 0; f < 4; ++f)
#pragma unroll
        for (int rr = 0; rr < 4; ++rr) {
          const int row = m0 + qm * 128 + wm * 64 + f * 16 + rg + rr;
          const float* hr = hb + (size_t)row * 1024 + ebase;
          float tmp = acA[f][0][rr] * hr[0] + acA[f][1][rr] * hr[16] +
                      acB[f][0][rr] * hr[128] + acB[f][1][rr] * hr[144];
#pragma unroll
          for (int s = 1; s < 16; s <<= 1) tmp += __shfl_xor(tmp, s);
          if (coll == 0) atomicAdd(&x[row * 8 + kidx], tmp);
        }
    }
  }
}

// ---- per-batch: S = sum tanh(x), vec = S*(gvec+bc), softmax, out/attn ----
__global__ __launch_bounds__(256) void finalize_k(
    const float* __restrict__ xk, const float* __restrict__ gvec,
    const float* __restrict__ bc, const float* __restrict__ ha,
    float* __restrict__ out, float* __restrict__ attn) {
  int b = blockIdx.x;
  int tid = threadIdx.x;
  float S = 0.f;
#pragma unroll
  for (int k = 0; k < 8; ++k) S += tanhf(xk[b * 8 + k]);
  float4 g4 = reinterpret_cast<const float4*>(gvec)[b * 256 + tid];
  float4 c4 = reinterpret_cast<const float4*>(bc)[tid];
  float v[4] = {S * (g4.x + c4.x), S * (g4.y + c4.y),
                S * (g4.z + c4.z), S * (g4.w + c4.w)};
  float mx = fmaxf(fmaxf(v[0], v[1]), fmaxf(v[2], v[3]));
  __shared__ float red[8];
#pragma unroll
  for (int off = 32; off >= 1; off >>= 1) mx = fmaxf(mx, __shfl_xor(mx, off));
  int lane = tid & 63, w = tid >> 6;
  if (lane == 0) red[w] = mx;
  __syncthreads();
  float m = fmaxf(fmaxf(red[0], red[1]), fmaxf(red[2], red[3]));
  float e[4], sum = 0.f;
#pragma unroll
  for (int s = 0; s < 4; ++s) { e[s] = __expf(v[s] - m); sum += e[s]; }
#pragma unroll
  for (int off = 32; off >= 1; off >>= 1) sum += __shfl_xor(sum, off);
  if (lane == 0) red[4 + w] = sum;
  __syncthreads();
  float inv = 1.f / (red[4] + red[5] + red[6] + red[7]);
  float4 h4 = reinterpret_cast<const float4*>(ha)[b * 256 + tid];
  float4 a4, o4;
  a4.x = e[0] * inv; a4.y = e[1] * inv; a4.z = e[2] * inv; a4.w = e[3] * inv;
  o4.x = fmaf(a4.x, h4.x, h4.x); o4.y = fmaf(a4.y, h4.y, h4.y);
  o4.z = fmaf(a4.z, h4.z, h4.z); o4.w = fmaf(a4.w, h4.w, h4.w);
  reinterpret_cast<float4*>(attn)[b * 256 + tid] = a4;
  reinterpret_cast<float4*>(out)[b * 256 + tid] = o4;
}

extern "C" void kernel_launch(void* const* d_in, const int* in_sizes, int n_in,
                              void* d_out, int out_size, void* d_ws, size_t ws_size,
                              hipStream_t stream) {
  const float* l_hidden = (const float*)d_in[0];
  const float* m_hidden = (const float*)d_in[1];
  const float* G_l_m = (const float*)d_in[2];
  const float* G_m_l = (const float*)d_in[3];
  const float* l_fc1_w = (const float*)d_in[4];
  const float* l_fc1_b = (const float*)d_in[5];
  const float* l_fc2_w = (const float*)d_in[6];
  const float* l_fc2_b = (const float*)d_in[7];
  const float* m_fc1_w = (const float*)d_in[8];
  const float* m_fc1_b = (const float*)d_in[9];
  const float* m_fc2_w = (const float*)d_in[10];
  const float* m_fc2_b = (const float*)d_in[11];
  float* out = (float*)d_out;

  char* ws = (char*)d_ws;
  unsigned short* Ahi = (unsigned short*)(ws);                    // 16 MB
  unsigned short* Alo = (unsigned short*)(ws + 16777216);         // 16 MB
  unsigned short* Bhi = (unsigned short*)(ws + 33554432);         // 18 MB (9216x1024)
  unsigned short* Blo = (unsigned short*)(ws + 52428800);         // 18 MB
  float* gvec = (float*)(ws + 71303168);                          // 32 MB
  float* x = (float*)(ws + 104857600);                            // 512 KB (2 dirs)
  float* bc = (float*)(ws + 105381888);                           // 4 KB

  hipMemsetAsync(x, 0, 2 * NB * 8 * sizeof(float), stream);

  dim3 gemmGrid(1152);
  dim3 prepGrid(17408);

  // direction l
  prep_k<<<prepGrid, 256, 0, stream>>>(l_hidden, G_l_m, l_fc1_w, l_fc1_b,
                                       l_fc2_w, l_fc2_b, 256, Ahi, Alo, Bhi, Blo, bc);
  gemm_k<<<gemmGrid, 512, 0, stream>>>(Ahi, Alo, Bhi, Blo, m_hidden, gvec, x);
  finalize_k<<<NB, 256, 0, stream>>>(x, gvec, bc, l_hidden, out, out + 2 * (size_t)NB * DD);

  // direction m
  prep_k<<<prepGrid, 256, 0, stream>>>(m_hidden, G_m_l, m_fc1_w, m_fc1_b,
                                       m_fc2_w, m_fc2_b, 128, Ahi, Alo, Bhi, Blo, bc);
  gemm_k<<<gemmGrid, 512, 0, stream>>>(Ahi, Alo, Bhi, Blo, l_hidden, gvec, x + NB * 8);
  finalize_k<<<NB, 256, 0, stream>>>(x + NB * 8, gvec, bc, m_hidden,
                                     out + (size_t)NB * DD, out + 3 * (size_t)NB * DD);
}